// Round 8
// baseline (380.356 us; speedup 1.0000x reference)
//
#include <hip/hip_runtime.h>
#include <math.h>

#define N_NODES 1024
#define B_SZ 64
#define GN 8192      // b*c flattened width of xg slot buffers
#define KI 384       // 3*128
#define EDIM 16

typedef _Float16 half8_t __attribute__((ext_vector_type(8)));
typedef float f32x4 __attribute__((ext_vector_type(4)));

__device__ __forceinline__ unsigned short f2h(float f) {
    _Float16 h = (_Float16)f;
    return *(unsigned short*)&h;
}
__device__ __forceinline__ float h2f(unsigned short u) {
    _Float16 h = *(_Float16*)&u;
    return (float)h;
}
__device__ __forceinline__ float sigmoidf_(float v) {
    return 1.f / (1.f + __expf(-v));
}
// async global->LDS, 16B per lane; lds base must be wave-uniform.
__device__ __forceinline__ void load_lds16(const void* g, void* l) {
    __builtin_amdgcn_global_load_lds(
        (const __attribute__((address_space(1))) void*)g,
        (__attribute__((address_space(3))) void*)l, 16, 0, 0);
}

// ---------------------------------------------------------------------------
// A = softmax(relu(E E^T)) row-wise -> Ah[n][m] and AhT[m][n] (fp16)
// ---------------------------------------------------------------------------
__global__ __launch_bounds__(256) void compute_A_kernel(
    const float* __restrict__ E, unsigned short* __restrict__ Ah,
    unsigned short* __restrict__ AhT) {
    __shared__ float red[256];
    const int tid = threadIdx.x;
    const int n = blockIdx.x;
    float en[EDIM];
#pragma unroll
    for (int e = 0; e < EDIM; ++e) en[e] = E[n * EDIM + e];
    float logit[4], lmax = -1e30f;
#pragma unroll
    for (int j = 0; j < 4; ++j) {
        const int m = tid + j * 256;
        float d = 0.f;
#pragma unroll
        for (int e = 0; e < EDIM; ++e) d += en[e] * E[m * EDIM + e];
        d = fmaxf(d, 0.f);
        logit[j] = d;
        lmax = fmaxf(lmax, d);
    }
    red[tid] = lmax;
    __syncthreads();
    for (int s = 128; s > 0; s >>= 1) {
        if (tid < s) red[tid] = fmaxf(red[tid], red[tid + s]);
        __syncthreads();
    }
    lmax = red[0];
    __syncthreads();
    float ex[4], lsum = 0.f;
#pragma unroll
    for (int j = 0; j < 4; ++j) {
        ex[j] = __expf(logit[j] - lmax);
        lsum += ex[j];
    }
    red[tid] = lsum;
    __syncthreads();
    for (int s = 128; s > 0; s >>= 1) {
        if (tid < s) red[tid] += red[tid + s];
        __syncthreads();
    }
    const float inv = 1.f / red[0];
#pragma unroll
    for (int j = 0; j < 4; ++j) {
        const int m = tid + j * 256;
        const unsigned short h = f2h(ex[j] * inv);
        Ah[n * N_NODES + m] = h;
        AhT[(size_t)m * N_NODES + n] = h;
    }
}

// ---------------------------------------------------------------------------
// T0[n][b*128+c] = concat(x,state)[b][n][c]  (fp16)
// ---------------------------------------------------------------------------
__global__ __launch_bounds__(256) void build_T0_kernel(
    const float* __restrict__ x, const float* __restrict__ state,
    unsigned short* __restrict__ T0) {
    const int n = blockIdx.x;
    const int tid = threadIdx.x;
#pragma unroll
    for (int t = 0; t < 32; ++t) {
        const int idx = t * 256 + tid;
        const int c = idx & 127;
        const int b = idx >> 7;
        const float v = (c < 64) ? x[((size_t)b * N_NODES + n) * 64 + c]
                                 : state[((size_t)b * N_NODES + n) * 64 + (c - 64)];
        T0[(size_t)n * GN + idx] = f2h(v);
    }
}

// ---------------------------------------------------------------------------
// T0T[bc][n] = T0[n][bc]  via LDS transpose. grid (ntile=16, b=64).
// ---------------------------------------------------------------------------
__global__ __launch_bounds__(256) void transpose_T0_kernel(
    const unsigned short* __restrict__ T0, unsigned short* __restrict__ T0T) {
    __shared__ unsigned short Ls[128 * 68];  // [c][n], pad 4
    const int tid = threadIdx.x;
    const int n0 = blockIdx.x * 64;
    const int b = blockIdx.y;
#pragma unroll
    for (int t = 0; t < 4; ++t) {
        const int id = t * 256 + tid;
        const int nl = id >> 4;
        const int c8 = id & 15;
        uint4 v = *(const uint4*)&T0[(size_t)(n0 + nl) * GN + b * 128 + c8 * 8];
        const unsigned short* vp = (const unsigned short*)&v;
#pragma unroll
        for (int j = 0; j < 8; ++j) Ls[(c8 * 8 + j) * 68 + nl] = vp[j];
    }
    __syncthreads();
    const int c = tid >> 1;
    const int half = tid & 1;
#pragma unroll
    for (int j = 0; j < 8; ++j) {
        uint2 v = *(const uint2*)&Ls[c * 68 + half * 32 + j * 4];
        *(uint2*)&T0T[(size_t)(b * 128 + c) * N_NODES + n0 + half * 32 + j * 4] =
            v;
    }
}

// ---------------------------------------------------------------------------
// S2h[n][m] = 2 * sum_k Ah[n][k]*AhT[m][k] - (n==m)   (fp16; S2 = 2A^2 - I)
// 64x64 tiles, grid (16,16). XOR-swizzled DMA staging like the big GEMMs.
// ---------------------------------------------------------------------------
__global__ __launch_bounds__(256) void gemm_s2_kernel(
    const unsigned short* __restrict__ Ah,
    const unsigned short* __restrict__ AhT, unsigned short* __restrict__ S2h) {
    __shared__ unsigned short As[64 * 64];
    __shared__ unsigned short Bs[64 * 64];
    const int tid = threadIdx.x;
    const int wave = tid >> 6;
    const int lane = tid & 63;
    const int l15 = lane & 15;
    const int quad = lane >> 4;
    const int n0 = blockIdx.x * 64;
    const int m0 = blockIdx.y * 64;
    const int wn = wave * 16;
    const int lr = lane >> 3;
    const int lsw = (lane & 7) ^ lr;

    f32x4 acc[4] = {};
    for (int k0 = 0; k0 < N_NODES; k0 += 64) {
#pragma unroll
        for (int i = 0; i < 2; ++i) {
            const int rbase = (wave * 2 + i) * 8;
            load_lds16(&Ah[(size_t)(n0 + rbase + lr) * N_NODES + k0 + lsw * 8],
                       &As[rbase * 64]);
            load_lds16(&AhT[(size_t)(m0 + rbase + lr) * N_NODES + k0 + lsw * 8],
                       &Bs[rbase * 64]);
        }
        __syncthreads();
#pragma unroll
        for (int ks = 0; ks < 2; ++ks) {
            const int slot = (((ks * 4 + quad)) ^ (l15 & 7)) * 8;
            const half8_t b = *(const half8_t*)&Bs[(wn + l15) * 64 + slot];
#pragma unroll
            for (int mi = 0; mi < 4; ++mi) {
                const half8_t a = *(const half8_t*)&As[(mi * 16 + l15) * 64 + slot];
                acc[mi] =
                    __builtin_amdgcn_mfma_f32_16x16x32_f16(a, b, acc[mi], 0, 0, 0);
            }
        }
        __syncthreads();
    }
#pragma unroll
    for (int mi = 0; mi < 4; ++mi) {
#pragma unroll
        for (int r = 0; r < 4; ++r) {
            const int n_g = n0 + mi * 16 + quad * 4 + r;
            const int m_g = m0 + wn + l15;
            const float v = 2.f * acc[mi][r] - (n_g == m_g ? 1.f : 0.f);
            S2h[(size_t)n_g * N_NODES + m_g] = f2h(v);
        }
    }
}

// ---------------------------------------------------------------------------
// Combined graph GEMM: [T1;T2] = [Ah;S2h] . T0T^T
//   rows 0..1023 -> T1 = A @ T0;  rows 1024..2047 -> T2 = S2 @ T0.
// 128x256 tile, BK=64, 4 waves (2x2 of 64x128). All staging via swizzled
// global_load_lds. Epilogue: two 64-row passes through Cs -> uint4 stores.
// grid (16, 32).
// ---------------------------------------------------------------------------
__global__ __launch_bounds__(256) void gemm_comb_kernel(
    const unsigned short* __restrict__ Ah,
    const unsigned short* __restrict__ S2h,
    const unsigned short* __restrict__ T0T,
    unsigned short* __restrict__ T1, unsigned short* __restrict__ T2) {
    __shared__ union {
        struct {
            unsigned short As[128 * 64];  // [m-local][k] swizzled
            unsigned short Bs[256 * 64];  // [bc-local][k] swizzled
        } s;
        unsigned short Cs[64 * 264];      // epilogue repack (one m-half)
    } lds;
    const int tid = threadIdx.x;
    const int wave = tid >> 6;
    const int lane = tid & 63;
    const int l15 = lane & 15;
    const int quad = lane >> 4;
    const int wm = (wave >> 1) * 64;
    const int wn = (wave & 1) * 128;
    const int mrow0 = blockIdx.x * 128;
    const int bc0 = blockIdx.y * 256;
    const unsigned short* Msrc =
        (mrow0 < N_NODES) ? Ah + (size_t)mrow0 * N_NODES
                          : S2h + (size_t)(mrow0 - N_NODES) * N_NODES;
    unsigned short* OUT = (mrow0 < N_NODES)
                              ? T1 + (size_t)mrow0 * GN
                              : T2 + (size_t)(mrow0 - N_NODES) * GN;
    const int lr = lane >> 3;
    const int lsw = (lane & 7) ^ lr;

    f32x4 acc[4][8] = {};

    for (int k0 = 0; k0 < N_NODES; k0 += 64) {
#pragma unroll
        for (int i = 0; i < 4; ++i) {
            const int rbase = (wave * 4 + i) * 8;
            load_lds16(&Msrc[(size_t)(rbase + lr) * N_NODES + k0 + lsw * 8],
                       &lds.s.As[rbase * 64]);
        }
#pragma unroll
        for (int i = 0; i < 8; ++i) {
            const int rbase = (wave * 8 + i) * 8;
            load_lds16(&T0T[(size_t)(bc0 + rbase + lr) * N_NODES + k0 + lsw * 8],
                       &lds.s.Bs[rbase * 64]);
        }
        __syncthreads();
#pragma unroll
        for (int ks = 0; ks < 2; ++ks) {
            const int slot = ((ks * 4 + quad) ^ (l15 & 7)) * 8;
            half8_t a[4], b[8];
#pragma unroll
            for (int mi = 0; mi < 4; ++mi)
                a[mi] = *(const half8_t*)&lds.s
                             .As[(wm + mi * 16 + l15) * 64 + slot];
#pragma unroll
            for (int ni = 0; ni < 8; ++ni)
                b[ni] = *(const half8_t*)&lds.s
                             .Bs[(wn + ni * 16 + l15) * 64 + slot];
#pragma unroll
            for (int mi = 0; mi < 4; ++mi)
#pragma unroll
                for (int ni = 0; ni < 8; ++ni)
                    acc[mi][ni] = __builtin_amdgcn_mfma_f32_16x16x32_f16(
                        a[mi], b[ni], acc[mi][ni], 0, 0, 0);
        }
        __syncthreads();
    }

    // epilogue: two m-half passes (rows p*64..p*64+63 of the 128-row tile)
#pragma unroll
    for (int p = 0; p < 2; ++p) {
        if (p) __syncthreads();
        if ((wave >> 1) == p) {
#pragma unroll
            for (int mi = 0; mi < 4; ++mi)
#pragma unroll
                for (int ni = 0; ni < 8; ++ni)
#pragma unroll
                    for (int r = 0; r < 4; ++r) {
                        const int row = mi * 16 + quad * 4 + r;  // 0..63
                        const int col = wn + ni * 16 + l15;      // 0..255
                        lds.Cs[row * 264 + col] = f2h(acc[mi][ni][r]);
                    }
        }
        __syncthreads();
#pragma unroll
        for (int i = 0; i < 8; ++i) {
            const int id = i * 256 + tid;  // 0..2047
            const int row = id >> 5;       // 0..63
            const int c8 = id & 31;
            uint4 cv = *(const uint4*)&lds.Cs[row * 264 + c8 * 8];
            *(uint4*)&OUT[(size_t)(p * 64 + row) * GN + bc0 + c8 * 8] = cv;
        }
    }
}

// ---------------------------------------------------------------------------
// Dequant: Wt[n][o][ki] = sum_e E[n,e]*Wp[e][ki][o]  (fp16, k-contig)
// Pool patch in registers, looped over 32 nodes/block.
// ---------------------------------------------------------------------------
__global__ __launch_bounds__(256) void dequant_kernel(
    const float* __restrict__ Wp, const float* __restrict__ E,
    unsigned short* __restrict__ Wt, int NO) {
    __shared__ float En[32 * 16];
    const int tid = threadIdx.x;
    const int ki0 = blockIdx.x * 32;
    const int o0 = blockIdx.y * 32;
    const int n0 = blockIdx.z * 32;
    const int o = tid >> 3;
    const int k4 = tid & 7;

#pragma unroll
    for (int t = 0; t < 2; ++t) {
        const int id = t * 256 + tid;
        En[id] = E[(n0 + (id >> 4)) * EDIM + (id & 15)];
    }
    __syncthreads();

    f32x4 w[EDIM];
#pragma unroll
    for (int e = 0; e < EDIM; ++e) {
        f32x4 v;
#pragma unroll
        for (int j = 0; j < 4; ++j)
            v[j] = Wp[(size_t)(e * KI + ki0 + k4 * 4 + j) * NO + o0 + o];
        w[e] = v;
    }

    const size_t wt_base = ((size_t)n0 * NO + (o0 + o)) * KI + ki0 + k4 * 4;
#pragma unroll 4
    for (int nl = 0; nl < 32; ++nl) {
        f32x4 a = {0.f, 0.f, 0.f, 0.f};
#pragma unroll
        for (int e = 0; e < EDIM; ++e) a += w[e] * En[nl * EDIM + e];
        union { unsigned short u[4]; uint2 v; } pk;
#pragma unroll
        for (int j = 0; j < 4; ++j) pk.u[j] = f2h(a[j]);
        *(uint2*)&Wt[wt_base + (size_t)nl * NO * KI] = pk.v;
    }
}

// ---------------------------------------------------------------------------
// Gate per-node GEMM (merged z+r): M=64(b), N=128(o), K=384 in 6 rounds of
// 64 ki (24 KB LDS -> 6 blocks/CU).  z -> T0/T0T state slice; r -> rbuf.
// ---------------------------------------------------------------------------
__global__ __launch_bounds__(256) void pernode_gate_kernel(
    const unsigned short* __restrict__ T0,
    const unsigned short* __restrict__ T1,
    const unsigned short* __restrict__ T2,
    const unsigned short* __restrict__ Wt, const float* __restrict__ E,
    const float* __restrict__ bp, const float* __restrict__ state,
    float* __restrict__ rbuf, unsigned short* __restrict__ t0_out,
    unsigned short* __restrict__ t0T_out) {
    __shared__ unsigned short Xs[64 * 64];   // [b][ki64] swizzled
    __shared__ unsigned short Ws[128 * 64];  // [o][ki64] swizzled
    const int n = blockIdx.x;
    const int tid = threadIdx.x;
    const int wave = tid >> 6;
    const int lane = tid & 63;
    const int l15 = lane & 15;
    const int quad = lane >> 4;
    const int wn = wave * 32;
    const int lr = lane >> 3;
    const int lsw = (lane & 7) ^ lr;

    float bias[2];
#pragma unroll
    for (int ni = 0; ni < 2; ++ni) {
        float bv = 0.f;
#pragma unroll
        for (int e = 0; e < EDIM; ++e)
            bv += E[n * EDIM + e] * bp[e * 128 + wn + ni * 16 + l15];
        bias[ni] = bv;
    }

    f32x4 acc[4][2] = {};

    for (int rd = 0; rd < 6; ++rd) {
        const unsigned short* Ts = (rd < 2) ? T0 : (rd < 4) ? T1 : T2;
        const int kio = (rd & 1) * 64;
        const unsigned short* xsrc = Ts + (size_t)n * GN;
#pragma unroll
        for (int i = 0; i < 2; ++i) {
            const int rbase = (wave * 2 + i) * 8;
            load_lds16(xsrc + (rbase + lr) * 128 + kio + lsw * 8,
                       &Xs[rbase * 64]);
        }
#pragma unroll
        for (int i = 0; i < 4; ++i) {
            const int rbase = (wave * 4 + i) * 8;
            load_lds16(
                Wt + ((size_t)n * 128 + rbase + lr) * KI + rd * 64 + lsw * 8,
                &Ws[rbase * 64]);
        }
        __syncthreads();
#pragma unroll
        for (int ks = 0; ks < 2; ++ks) {
            const int slot = ((ks * 4 + quad) ^ (l15 & 7)) * 8;
            half8_t b[2];
#pragma unroll
            for (int ni = 0; ni < 2; ++ni)
                b[ni] = *(const half8_t*)&Ws[(wn + ni * 16 + l15) * 64 + slot];
#pragma unroll
            for (int mi = 0; mi < 4; ++mi) {
                const half8_t a =
                    *(const half8_t*)&Xs[(mi * 16 + l15) * 64 + slot];
#pragma unroll
                for (int ni = 0; ni < 2; ++ni)
                    acc[mi][ni] = __builtin_amdgcn_mfma_f32_16x16x32_f16(
                        a, b[ni], acc[mi][ni], 0, 0, 0);
            }
        }
        __syncthreads();
    }

#pragma unroll
    for (int mi = 0; mi < 4; ++mi) {
#pragma unroll
        for (int r = 0; r < 4; ++r) {
            const int b_g = mi * 16 + quad * 4 + r;
#pragma unroll
            for (int ni = 0; ni < 2; ++ni) {
                const int o_g = wn + ni * 16 + l15;
                const float v = sigmoidf_(acc[mi][ni][r] + bias[ni]);
                if (o_g < 64) {  // z -> candidate slice (both layouts)
                    const float sv =
                        state[((size_t)b_g * N_NODES + n) * 64 + o_g];
                    const unsigned short zh = f2h(v * sv);
                    t0_out[(size_t)n * GN + b_g * 128 + 64 + o_g] = zh;
                    t0T_out[(size_t)(b_g * 128 + 64 + o_g) * N_NODES + n] = zh;
                } else {  // r
                    rbuf[((size_t)n * B_SZ + b_g) * 64 + (o_g - 64)] = v;
                }
            }
        }
    }
}

// ---------------------------------------------------------------------------
// Update per-node GEMM: out = r*state + (1-r)*tanh(acc+bias). N=64,
// 6 rounds of 64 ki (16 KB LDS -> 8 blocks/CU).
// ---------------------------------------------------------------------------
__global__ __launch_bounds__(256) void pernode_upd_kernel(
    const unsigned short* __restrict__ T0,
    const unsigned short* __restrict__ T1,
    const unsigned short* __restrict__ T2,
    const unsigned short* __restrict__ Wt, const float* __restrict__ E,
    const float* __restrict__ bp, const float* __restrict__ state,
    const float* __restrict__ rbuf, float* __restrict__ out) {
    __shared__ unsigned short Xs[64 * 64];  // [b][ki64] swizzled
    __shared__ unsigned short Ws[64 * 64];  // [o][ki64] swizzled
    const int n = blockIdx.x;
    const int tid = threadIdx.x;
    const int wave = tid >> 6;
    const int lane = tid & 63;
    const int l15 = lane & 15;
    const int quad = lane >> 4;
    const int wn = wave * 16;
    const int o_g = wn + l15;
    const int lr = lane >> 3;
    const int lsw = (lane & 7) ^ lr;

    float bias = 0.f;
#pragma unroll
    for (int e = 0; e < EDIM; ++e)
        bias += E[n * EDIM + e] * bp[e * 64 + o_g];

    f32x4 acc[4] = {};

    for (int rd = 0; rd < 6; ++rd) {
        const unsigned short* Ts = (rd < 2) ? T0 : (rd < 4) ? T1 : T2;
        const int kio = (rd & 1) * 64;
        const unsigned short* xsrc = Ts + (size_t)n * GN;
#pragma unroll
        for (int i = 0; i < 2; ++i) {
            const int rbase = (wave * 2 + i) * 8;
            load_lds16(xsrc + (rbase + lr) * 128 + kio + lsw * 8,
                       &Xs[rbase * 64]);
        }
#pragma unroll
        for (int i = 0; i < 2; ++i) {
            const int rbase = (wave * 2 + i) * 8;
            load_lds16(
                Wt + ((size_t)n * 64 + rbase + lr) * KI + rd * 64 + lsw * 8,
                &Ws[rbase * 64]);
        }
        __syncthreads();
#pragma unroll
        for (int ks = 0; ks < 2; ++ks) {
            const int slot = ((ks * 4 + quad) ^ (l15 & 7)) * 8;
            const half8_t b = *(const half8_t*)&Ws[(wn + l15) * 64 + slot];
#pragma unroll
            for (int mi = 0; mi < 4; ++mi) {
                const half8_t a =
                    *(const half8_t*)&Xs[(mi * 16 + l15) * 64 + slot];
                acc[mi] =
                    __builtin_amdgcn_mfma_f32_16x16x32_f16(a, b, acc[mi], 0, 0, 0);
            }
        }
        __syncthreads();
    }

#pragma unroll
    for (int mi = 0; mi < 4; ++mi) {
#pragma unroll
        for (int r = 0; r < 4; ++r) {
            const int b_g = mi * 16 + quad * 4 + r;
            const float hc = tanhf(acc[mi][r] + bias);
            const float rr = rbuf[((size_t)n * B_SZ + b_g) * 64 + o_g];
            const float sv = state[((size_t)b_g * N_NODES + n) * 64 + o_g];
            out[((size_t)b_g * N_NODES + n) * 64 + o_g] =
                rr * sv + (1.f - rr) * hc;
        }
    }
}

// ---------------------------------------------------------------------------
extern "C" void kernel_launch(void* const* d_in, const int* in_sizes, int n_in,
                              void* d_out, int out_size, void* d_ws,
                              size_t ws_size, hipStream_t stream) {
    const float* x = (const float*)d_in[0];
    const float* state = (const float*)d_in[1];
    const float* E = (const float*)d_in[2];
    const float* gW = (const float*)d_in[3];  // (16,3,128,128)
    const float* gb = (const float*)d_in[4];  // (16,128)
    const float* uW = (const float*)d_in[5];  // (16,3,128,64)
    const float* ub = (const float*)d_in[6];  // (16,64)
    float* out = (float*)d_out;

    char* ws = (char*)d_ws;
    unsigned short* Ah = (unsigned short*)ws;                  //  2.10 MB
    unsigned short* AhT = (unsigned short*)(ws + 2097152);     //  2.10 MB
    unsigned short* S2h = (unsigned short*)(ws + 4194304);     //  2.10 MB
    unsigned short* T0 = (unsigned short*)(ws + 6291456);      // 16.78 MB
    unsigned short* T0T = (unsigned short*)(ws + 23068672);    // 16.78 MB
    unsigned short* T1 = (unsigned short*)(ws + 39845888);     // 16.78 MB
    unsigned short* T2 = (unsigned short*)(ws + 56623104);     // 16.78 MB
    unsigned short* Wt = (unsigned short*)(ws + 73400320);     // 100.66 MB
    float* rbuf = (float*)(ws + 174063616);                    // 16.78 MB
    // total 190.8 MB (ws = 256 MB)

    compute_A_kernel<<<N_NODES, 256, 0, stream>>>(E, Ah, AhT);
    build_T0_kernel<<<N_NODES, 256, 0, stream>>>(x, state, T0);
    transpose_T0_kernel<<<dim3(16, 64), 256, 0, stream>>>(T0, T0T);
    gemm_s2_kernel<<<dim3(16, 16), 256, 0, stream>>>(Ah, AhT, S2h);

    // --- avwgcn #1 (gate) ---
    dequant_kernel<<<dim3(12, 4, 32), 256, 0, stream>>>(gW, E, Wt, 128);
    gemm_comb_kernel<<<dim3(16, 32), 256, 0, stream>>>(Ah, S2h, T0T, T1, T2);
    pernode_gate_kernel<<<N_NODES, 256, 0, stream>>>(T0, T1, T2, Wt, E, gb,
                                                     state, rbuf, T0, T0T);

    // --- avwgcn #2 (update); T0/T0T now hold candidate = [x, z*state] ---
    dequant_kernel<<<dim3(12, 2, 32), 256, 0, stream>>>(uW, E, Wt, 64);
    gemm_comb_kernel<<<dim3(16, 32), 256, 0, stream>>>(Ah, S2h, T0T, T1, T2);
    pernode_upd_kernel<<<N_NODES, 256, 0, stream>>>(T0, T1, T2, Wt, E, ub,
                                                    state, rbuf, out);
}

// Round 9
// 331.641 us; speedup vs baseline: 1.1469x; 1.1469x over previous
//
#include <hip/hip_runtime.h>
#include <math.h>

#define N_NODES 1024
#define B_SZ 64
#define GNH 4096     // half-width: b*64+c layout for X or S plane
#define KI 384       // 3*128
#define EDIM 16

typedef _Float16 half8_t __attribute__((ext_vector_type(8)));
typedef float f32x4 __attribute__((ext_vector_type(4)));

__device__ __forceinline__ unsigned short f2h(float f) {
    _Float16 h = (_Float16)f;
    return *(unsigned short*)&h;
}
__device__ __forceinline__ float h2f(unsigned short u) {
    _Float16 h = *(_Float16*)&u;
    return (float)h;
}
__device__ __forceinline__ float sigmoidf_(float v) {
    return 1.f / (1.f + __expf(-v));
}
// async global->LDS, 16B per lane; lds base must be wave-uniform.
__device__ __forceinline__ void load_lds16(const void* g, void* l) {
    __builtin_amdgcn_global_load_lds(
        (const __attribute__((address_space(1))) void*)g,
        (__attribute__((address_space(3))) void*)l, 16, 0, 0);
}

// ---------------------------------------------------------------------------
// A = softmax(relu(E E^T)) row-wise -> Ah[n][m]  (fp16, coalesced only)
// ---------------------------------------------------------------------------
__global__ __launch_bounds__(256) void compute_A_kernel(
    const float* __restrict__ E, unsigned short* __restrict__ Ah) {
    __shared__ float red[256];
    const int tid = threadIdx.x;
    const int n = blockIdx.x;
    float en[EDIM];
#pragma unroll
    for (int e = 0; e < EDIM; ++e) en[e] = E[n * EDIM + e];
    float logit[4], lmax = -1e30f;
#pragma unroll
    for (int j = 0; j < 4; ++j) {
        const int m = tid + j * 256;
        float d = 0.f;
#pragma unroll
        for (int e = 0; e < EDIM; ++e) d += en[e] * E[m * EDIM + e];
        d = fmaxf(d, 0.f);
        logit[j] = d;
        lmax = fmaxf(lmax, d);
    }
    red[tid] = lmax;
    __syncthreads();
    for (int s = 128; s > 0; s >>= 1) {
        if (tid < s) red[tid] = fmaxf(red[tid], red[tid + s]);
        __syncthreads();
    }
    lmax = red[0];
    __syncthreads();
    float ex[4], lsum = 0.f;
#pragma unroll
    for (int j = 0; j < 4; ++j) {
        ex[j] = __expf(logit[j] - lmax);
        lsum += ex[j];
    }
    red[tid] = lsum;
    __syncthreads();
    for (int s = 128; s > 0; s >>= 1) {
        if (tid < s) red[tid] += red[tid + s];
        __syncthreads();
    }
    const float inv = 1.f / red[0];
#pragma unroll
    for (int j = 0; j < 4; ++j)
        Ah[n * N_NODES + tid + j * 256] = f2h(ex[j] * inv);
}

// ---------------------------------------------------------------------------
// build: TX0[n][b*64+c] = x[b][n][c];  TS0[n][b*64+c] = state[b][n][c]
// ---------------------------------------------------------------------------
__global__ __launch_bounds__(256) void build_T0_kernel(
    const float* __restrict__ x, const float* __restrict__ state,
    unsigned short* __restrict__ TX0, unsigned short* __restrict__ TS0) {
    const int n = blockIdx.x;
    const int tid = threadIdx.x;
#pragma unroll
    for (int t = 0; t < 32; ++t) {
        const int idx = t * 256 + tid;
        const int c = idx & 127;
        const int b = idx >> 7;
        if (c < 64)
            TX0[(size_t)n * GNH + b * 64 + c] =
                f2h(x[((size_t)b * N_NODES + n) * 64 + c]);
        else
            TS0[(size_t)n * GNH + b * 64 + (c - 64)] =
                f2h(state[((size_t)b * N_NODES + n) * 64 + (c - 64)]);
    }
}

// ---------------------------------------------------------------------------
// Generic fp16 transpose: dst[c][1024] = src[r][W], 64x64 tiles.
// grid (1024/64, W/64).
// ---------------------------------------------------------------------------
__global__ __launch_bounds__(256) void transpose16_kernel(
    const unsigned short* __restrict__ src, unsigned short* __restrict__ dst,
    int W) {
    __shared__ unsigned short Ls[64 * 72];  // pad 8 -> 16B-aligned rows
    const int tid = threadIdx.x;
    const int r0 = blockIdx.x * 64;
    const int c0 = blockIdx.y * 64;
#pragma unroll
    for (int t = 0; t < 2; ++t) {
        const int id = t * 256 + tid;
        const int row = id >> 3;
        const int c8 = id & 7;
        uint4 v = *(const uint4*)&src[(size_t)(r0 + row) * W + c0 + c8 * 8];
        const unsigned short* vp = (const unsigned short*)&v;
#pragma unroll
        for (int j = 0; j < 8; ++j) Ls[(c8 * 8 + j) * 72 + row] = vp[j];
    }
    __syncthreads();
#pragma unroll
    for (int t = 0; t < 2; ++t) {
        const int id = t * 256 + tid;
        const int c = id >> 3;
        const int r8 = id & 7;
        uint4 v = *(const uint4*)&Ls[c * 72 + r8 * 8];
        *(uint4*)&dst[(size_t)(c0 + c) * N_NODES + r0 + r8 * 8] = v;
    }
}

// ---------------------------------------------------------------------------
// S2h[n][m] = 2 * sum_k Ah[n][k]*AhT[m][k] - (n==m)   (S2 = 2A^2 - I)
// ---------------------------------------------------------------------------
__global__ __launch_bounds__(256) void gemm_s2_kernel(
    const unsigned short* __restrict__ Ah,
    const unsigned short* __restrict__ AhT, unsigned short* __restrict__ S2h) {
    __shared__ unsigned short As[64 * 64];
    __shared__ unsigned short Bs[64 * 64];
    const int tid = threadIdx.x;
    const int wave = tid >> 6;
    const int lane = tid & 63;
    const int l15 = lane & 15;
    const int quad = lane >> 4;
    const int n0 = blockIdx.x * 64;
    const int m0 = blockIdx.y * 64;
    const int wn = wave * 16;
    const int lr = lane >> 3;
    const int lsw = (lane & 7) ^ lr;

    f32x4 acc[4] = {};
    for (int k0 = 0; k0 < N_NODES; k0 += 64) {
#pragma unroll
        for (int i = 0; i < 2; ++i) {
            const int rbase = (wave * 2 + i) * 8;
            load_lds16(&Ah[(size_t)(n0 + rbase + lr) * N_NODES + k0 + lsw * 8],
                       &As[rbase * 64]);
            load_lds16(&AhT[(size_t)(m0 + rbase + lr) * N_NODES + k0 + lsw * 8],
                       &Bs[rbase * 64]);
        }
        __syncthreads();
#pragma unroll
        for (int ks = 0; ks < 2; ++ks) {
            const int slot = ((ks * 4 + quad) ^ (l15 & 7)) * 8;
            const half8_t b = *(const half8_t*)&Bs[(wn + l15) * 64 + slot];
#pragma unroll
            for (int mi = 0; mi < 4; ++mi) {
                const half8_t a = *(const half8_t*)&As[(mi * 16 + l15) * 64 + slot];
                acc[mi] =
                    __builtin_amdgcn_mfma_f32_16x16x32_f16(a, b, acc[mi], 0, 0, 0);
            }
        }
        __syncthreads();
    }
#pragma unroll
    for (int mi = 0; mi < 4; ++mi) {
#pragma unroll
        for (int r = 0; r < 4; ++r) {
            const int n_g = n0 + mi * 16 + quad * 4 + r;
            const int m_g = m0 + wn + l15;
            const float v = 2.f * acc[mi][r] - (n_g == m_g ? 1.f : 0.f);
            S2h[(size_t)n_g * N_NODES + m_g] = f2h(v);
        }
    }
}

// ---------------------------------------------------------------------------
// Graph GEMM: 128x128 tile, BK=64, rows [A;S2] (bx<8 -> A -> T1•, else S2 ->
// T2•); cols: by<ysplit -> X plane (BTX/T1X/T2X) else S plane. No correction,
// no transposed epilogue. grid (16, ytiles).
// ---------------------------------------------------------------------------
__global__ __launch_bounds__(256) void gemm_graph_kernel(
    const unsigned short* __restrict__ Ah,
    const unsigned short* __restrict__ S2h,
    const unsigned short* __restrict__ BTX,
    const unsigned short* __restrict__ BTS,
    unsigned short* __restrict__ T1X, unsigned short* __restrict__ T1S,
    unsigned short* __restrict__ T2X, unsigned short* __restrict__ T2S,
    int ysplit) {
    __shared__ union {
        struct {
            unsigned short As[128 * 64];  // [m-local][k] swizzled
            unsigned short Bs[128 * 64];  // [col-local][k] swizzled
        } s;
        unsigned short Cs[128 * 136];     // epilogue repack
    } lds;
    const int tid = threadIdx.x;
    const int wave = tid >> 6;
    const int lane = tid & 63;
    const int l15 = lane & 15;
    const int quad = lane >> 4;
    const int wm = (wave >> 1) * 64;
    const int wn = (wave & 1) * 64;
    const int mrow0 = blockIdx.x * 128;
    const bool isA = mrow0 < N_NODES;
    const unsigned short* Asrc =
        (isA ? Ah : S2h) + (size_t)(mrow0 & 1023) * N_NODES;
    const bool isX = (int)blockIdx.y < ysplit;
    const int col0 = (isX ? blockIdx.y : blockIdx.y - ysplit) * 128;
    const unsigned short* Bsrc =
        (isX ? BTX : BTS) + (size_t)col0 * N_NODES;
    unsigned short* OUT =
        (isA ? (isX ? T1X : T1S) : (isX ? T2X : T2S)) +
        (size_t)(mrow0 & 1023) * GNH + col0;
    const int lr = lane >> 3;
    const int lsw = (lane & 7) ^ lr;

    f32x4 acc[4][4] = {};

    for (int k0 = 0; k0 < N_NODES; k0 += 64) {
#pragma unroll
        for (int i = 0; i < 4; ++i) {
            const int rbase = (wave * 4 + i) * 8;
            load_lds16(&Asrc[(size_t)(rbase + lr) * N_NODES + k0 + lsw * 8],
                       &lds.s.As[rbase * 64]);
        }
#pragma unroll
        for (int i = 0; i < 4; ++i) {
            const int rbase = (wave * 4 + i) * 8;
            load_lds16(&Bsrc[(size_t)(rbase + lr) * N_NODES + k0 + lsw * 8],
                       &lds.s.Bs[rbase * 64]);
        }
        __syncthreads();
#pragma unroll
        for (int ks = 0; ks < 2; ++ks) {
            const int slot = ((ks * 4 + quad) ^ (l15 & 7)) * 8;
            half8_t a[4], b[4];
#pragma unroll
            for (int mi = 0; mi < 4; ++mi)
                a[mi] = *(const half8_t*)&lds.s
                             .As[(wm + mi * 16 + l15) * 64 + slot];
#pragma unroll
            for (int ni = 0; ni < 4; ++ni)
                b[ni] = *(const half8_t*)&lds.s
                             .Bs[(wn + ni * 16 + l15) * 64 + slot];
#pragma unroll
            for (int mi = 0; mi < 4; ++mi)
#pragma unroll
                for (int ni = 0; ni < 4; ++ni)
                    acc[mi][ni] = __builtin_amdgcn_mfma_f32_16x16x32_f16(
                        a[mi], b[ni], acc[mi][ni], 0, 0, 0);
        }
        __syncthreads();
    }

#pragma unroll
    for (int mi = 0; mi < 4; ++mi)
#pragma unroll
        for (int ni = 0; ni < 4; ++ni)
#pragma unroll
            for (int r = 0; r < 4; ++r) {
                const int row = wm + mi * 16 + quad * 4 + r;
                const int col = wn + ni * 16 + l15;
                lds.Cs[row * 136 + col] = f2h(acc[mi][ni][r]);
            }
    __syncthreads();
#pragma unroll
    for (int i = 0; i < 8; ++i) {
        const int id = i * 256 + tid;
        const int row = id >> 4;
        const int c8 = id & 15;
        uint4 cv = *(const uint4*)&lds.Cs[row * 136 + c8 * 8];
        *(uint4*)&OUT[(size_t)row * GNH + c8 * 8] = cv;
    }
}

// ---------------------------------------------------------------------------
// Dequant: Wt[n][o][ki] = sum_e E[n,e]*Wp[e][ki][o]  (fp16, k-contig)
// ---------------------------------------------------------------------------
__global__ __launch_bounds__(256) void dequant_kernel(
    const float* __restrict__ Wp, const float* __restrict__ E,
    unsigned short* __restrict__ Wt, int NO) {
    __shared__ float En[32 * 16];
    const int tid = threadIdx.x;
    const int ki0 = blockIdx.x * 32;
    const int o0 = blockIdx.y * 32;
    const int n0 = blockIdx.z * 32;
    const int o = tid >> 3;
    const int k4 = tid & 7;

#pragma unroll
    for (int t = 0; t < 2; ++t) {
        const int id = t * 256 + tid;
        En[id] = E[(n0 + (id >> 4)) * EDIM + (id & 15)];
    }
    __syncthreads();

    f32x4 w[EDIM];
#pragma unroll
    for (int e = 0; e < EDIM; ++e) {
        f32x4 v;
#pragma unroll
        for (int j = 0; j < 4; ++j)
            v[j] = Wp[(size_t)(e * KI + ki0 + k4 * 4 + j) * NO + o0 + o];
        w[e] = v;
    }

    const size_t wt_base = ((size_t)n0 * NO + (o0 + o)) * KI + ki0 + k4 * 4;
#pragma unroll 4
    for (int nl = 0; nl < 32; ++nl) {
        f32x4 a = {0.f, 0.f, 0.f, 0.f};
#pragma unroll
        for (int e = 0; e < EDIM; ++e) a += w[e] * En[nl * EDIM + e];
        union { unsigned short u[4]; uint2 v; } pk;
#pragma unroll
        for (int j = 0; j < 4; ++j) pk.u[j] = f2h(a[j]);
        *(uint2*)&Wt[wt_base + (size_t)nl * NO * KI] = pk.v;
    }
}

// ---------------------------------------------------------------------------
// Gate per-node GEMM (merged z+r): M=64(b), N=128(o), K=384 in 3 tier rounds
// of 128 ki (XsX/XsS 64x64 planes + Ws 128x128; 48 KB LDS).
//   z (o<64)  -> TS0 = z*state (row-major) and TS0T (transposed)
//   r (o>=64) -> rbuf
// ---------------------------------------------------------------------------
__global__ __launch_bounds__(256) void pernode_gate_kernel(
    const unsigned short* __restrict__ TX0,
    const unsigned short* __restrict__ TS0,
    const unsigned short* __restrict__ TX1,
    const unsigned short* __restrict__ TS1,
    const unsigned short* __restrict__ TX2,
    const unsigned short* __restrict__ TS2,
    const unsigned short* __restrict__ Wt, const float* __restrict__ E,
    const float* __restrict__ bp, const float* __restrict__ state,
    float* __restrict__ rbuf, unsigned short* __restrict__ ts0_out,
    unsigned short* __restrict__ ts0T_out) {
    __shared__ unsigned short XsX[64 * 64];   // [b][kseg 0..7] swizzled
    __shared__ unsigned short XsS[64 * 64];   // [b][kseg 8..15] swizzled
    __shared__ unsigned short Ws[128 * 128];  // [o][k] swizzled (^row&15)
    const int n = blockIdx.x;
    const int tid = threadIdx.x;
    const int wave = tid >> 6;
    const int lane = tid & 63;
    const int l15 = lane & 15;
    const int quad = lane >> 4;
    const int wn = wave * 32;
    const int lr = lane >> 3;
    const int lsw = (lane & 7) ^ lr;
    const int lr4 = lane >> 4;

    float bias[2];
#pragma unroll
    for (int ni = 0; ni < 2; ++ni) {
        float bv = 0.f;
#pragma unroll
        for (int e = 0; e < EDIM; ++e)
            bv += E[n * EDIM + e] * bp[e * 128 + wn + ni * 16 + l15];
        bias[ni] = bv;
    }

    f32x4 acc[4][2] = {};

    const unsigned short* TXs[3] = {TX0, TX1, TX2};
    const unsigned short* TSs[3] = {TS0, TS1, TS2};

    for (int s = 0; s < 3; ++s) {
        const unsigned short* xs = TXs[s] + (size_t)n * GNH;
        const unsigned short* ss = TSs[s] + (size_t)n * GNH;
#pragma unroll
        for (int i = 0; i < 2; ++i) {
            const int slab = wave * 2 + i;  // 8 slabs of 8 b-rows
            load_lds16(xs + (slab * 8 + lr) * 64 + lsw * 8, &XsX[slab * 512]);
            load_lds16(ss + (slab * 8 + lr) * 64 + lsw * 8, &XsS[slab * 512]);
        }
#pragma unroll
        for (int i = 0; i < 8; ++i) {
            const int chunk = wave * 8 + i;            // 0..31
            const int orow = chunk * 4 + lr4;          // 4 o-rows per chunk
            const int sw = (lane & 15) ^ (orow & 15);
            load_lds16(Wt + ((size_t)n * 128 + orow) * KI + s * 128 + sw * 8,
                       &Ws[chunk * 512]);
        }
        __syncthreads();
#pragma unroll
        for (int ks = 0; ks < 4; ++ks) {
            const int kseg = ks * 4 + quad;                 // 0..15
            const int bslot = (kseg ^ l15) * 8;             // Ws
            const unsigned short* plane = (kseg < 8) ? XsX : XsS;
            const int aslot = ((kseg & 7) ^ (l15 & 7)) * 8; // plane
            half8_t b[2];
#pragma unroll
            for (int ni = 0; ni < 2; ++ni)
                b[ni] = *(const half8_t*)&Ws[(wn + ni * 16 + l15) * 128 + bslot];
#pragma unroll
            for (int mi = 0; mi < 4; ++mi) {
                const half8_t a =
                    *(const half8_t*)&plane[(mi * 16 + l15) * 64 + aslot];
#pragma unroll
                for (int ni = 0; ni < 2; ++ni)
                    acc[mi][ni] = __builtin_amdgcn_mfma_f32_16x16x32_f16(
                        a, b[ni], acc[mi][ni], 0, 0, 0);
            }
        }
        __syncthreads();
    }

#pragma unroll
    for (int mi = 0; mi < 4; ++mi) {
#pragma unroll
        for (int r = 0; r < 4; ++r) {
            const int b_g = mi * 16 + quad * 4 + r;
#pragma unroll
            for (int ni = 0; ni < 2; ++ni) {
                const int o_g = wn + ni * 16 + l15;
                const float v = sigmoidf_(acc[mi][ni][r] + bias[ni]);
                if (o_g < 64) {  // z -> candidate state slice (both layouts)
                    const float sv =
                        state[((size_t)b_g * N_NODES + n) * 64 + o_g];
                    const unsigned short zh = f2h(v * sv);
                    ts0_out[(size_t)n * GNH + b_g * 64 + o_g] = zh;
                    ts0T_out[(size_t)(b_g * 64 + o_g) * N_NODES + n] = zh;
                } else {  // r
                    rbuf[((size_t)n * B_SZ + b_g) * 64 + (o_g - 64)] = v;
                }
            }
        }
    }
}

// ---------------------------------------------------------------------------
// Update per-node GEMM: out = r*state + (1-r)*tanh(acc+bias). N=64, 32 KB LDS.
// ---------------------------------------------------------------------------
__global__ __launch_bounds__(256) void pernode_upd_kernel(
    const unsigned short* __restrict__ TX0,
    const unsigned short* __restrict__ TS0,
    const unsigned short* __restrict__ TX1,
    const unsigned short* __restrict__ TS1,
    const unsigned short* __restrict__ TX2,
    const unsigned short* __restrict__ TS2,
    const unsigned short* __restrict__ Wt, const float* __restrict__ E,
    const float* __restrict__ bp, const float* __restrict__ state,
    const float* __restrict__ rbuf, float* __restrict__ out) {
    __shared__ unsigned short XsX[64 * 64];
    __shared__ unsigned short XsS[64 * 64];
    __shared__ unsigned short Ws[64 * 128];
    const int n = blockIdx.x;
    const int tid = threadIdx.x;
    const int wave = tid >> 6;
    const int lane = tid & 63;
    const int l15 = lane & 15;
    const int quad = lane >> 4;
    const int wn = wave * 16;
    const int o_g = wn + l15;
    const int lr = lane >> 3;
    const int lsw = (lane & 7) ^ lr;
    const int lr4 = lane >> 4;

    float bias = 0.f;
#pragma unroll
    for (int e = 0; e < EDIM; ++e)
        bias += E[n * EDIM + e] * bp[e * 64 + o_g];

    f32x4 acc[4] = {};

    const unsigned short* TXs[3] = {TX0, TX1, TX2};
    const unsigned short* TSs[3] = {TS0, TS1, TS2};

    for (int s = 0; s < 3; ++s) {
        const unsigned short* xs = TXs[s] + (size_t)n * GNH;
        const unsigned short* ss = TSs[s] + (size_t)n * GNH;
#pragma unroll
        for (int i = 0; i < 2; ++i) {
            const int slab = wave * 2 + i;
            load_lds16(xs + (slab * 8 + lr) * 64 + lsw * 8, &XsX[slab * 512]);
            load_lds16(ss + (slab * 8 + lr) * 64 + lsw * 8, &XsS[slab * 512]);
        }
#pragma unroll
        for (int i = 0; i < 4; ++i) {
            const int chunk = wave * 4 + i;            // 0..15
            const int orow = chunk * 4 + lr4;
            const int sw = (lane & 15) ^ (orow & 15);
            load_lds16(Wt + ((size_t)n * 64 + orow) * KI + s * 128 + sw * 8,
                       &Ws[chunk * 512]);
        }
        __syncthreads();
#pragma unroll
        for (int ks = 0; ks < 4; ++ks) {
            const int kseg = ks * 4 + quad;
            const int bslot = (kseg ^ l15) * 8;
            const unsigned short* plane = (kseg < 8) ? XsX : XsS;
            const int aslot = ((kseg & 7) ^ (l15 & 7)) * 8;
            const half8_t b = *(const half8_t*)&Ws[(wn + l15) * 128 + bslot];
#pragma unroll
            for (int mi = 0; mi < 4; ++mi) {
                const half8_t a =
                    *(const half8_t*)&plane[(mi * 16 + l15) * 64 + aslot];
                acc[mi] =
                    __builtin_amdgcn_mfma_f32_16x16x32_f16(a, b, acc[mi], 0, 0, 0);
            }
        }
        __syncthreads();
    }

#pragma unroll
    for (int mi = 0; mi < 4; ++mi) {
#pragma unroll
        for (int r = 0; r < 4; ++r) {
            const int b_g = mi * 16 + quad * 4 + r;
            const float hc = tanhf(acc[mi][r] + bias);
            const float rr = rbuf[((size_t)n * B_SZ + b_g) * 64 + o_g];
            const float sv = state[((size_t)b_g * N_NODES + n) * 64 + o_g];
            out[((size_t)b_g * N_NODES + n) * 64 + o_g] =
                rr * sv + (1.f - rr) * hc;
        }
    }
}

// ---------------------------------------------------------------------------
extern "C" void kernel_launch(void* const* d_in, const int* in_sizes, int n_in,
                              void* d_out, int out_size, void* d_ws,
                              size_t ws_size, hipStream_t stream) {
    const float* x = (const float*)d_in[0];
    const float* state = (const float*)d_in[1];
    const float* E = (const float*)d_in[2];
    const float* gW = (const float*)d_in[3];  // (16,3,128,128)
    const float* gb = (const float*)d_in[4];  // (16,128)
    const float* uW = (const float*)d_in[5];  // (16,3,128,64)
    const float* ub = (const float*)d_in[6];  // (16,64)
    float* out = (float*)d_out;

    char* ws = (char*)d_ws;
    unsigned short* Ah = (unsigned short*)ws;                 //  2.10 MB
    unsigned short* AhT = (unsigned short*)(ws + 2097152);    //  2.10 MB
    unsigned short* S2h = (unsigned short*)(ws + 4194304);    //  2.10 MB
    unsigned short* TX0 = (unsigned short*)(ws + 6291456);    //  8.39 MB
    unsigned short* TS0 = (unsigned short*)(ws + 14680064);
    unsigned short* TX0T = (unsigned short*)(ws + 23068672);
    unsigned short* TS0T = (unsigned short*)(ws + 31457280);
    unsigned short* TX1 = (unsigned short*)(ws + 39845888);
    unsigned short* TS1 = (unsigned short*)(ws + 48234496);
    unsigned short* TX2 = (unsigned short*)(ws + 56623104);
    unsigned short* TS2 = (unsigned short*)(ws + 65011712);
    unsigned short* Wt = (unsigned short*)(ws + 73400320);    // 100.66 MB
    float* rbuf = (float*)(ws + 174063616);                   //  16.78 MB
    // total 190.8 MB (ws = 256 MB)

    compute_A_kernel<<<N_NODES, 256, 0, stream>>>(E, Ah);
    build_T0_kernel<<<N_NODES, 256, 0, stream>>>(x, state, TX0, TS0);
    transpose16_kernel<<<dim3(16, 16), 256, 0, stream>>>(Ah, AhT, N_NODES);
    transpose16_kernel<<<dim3(16, 64), 256, 0, stream>>>(TX0, TX0T, GNH);
    transpose16_kernel<<<dim3(16, 64), 256, 0, stream>>>(TS0, TS0T, GNH);
    gemm_s2_kernel<<<dim3(16, 16), 256, 0, stream>>>(Ah, AhT, S2h);

    // --- avwgcn #1 (gate): both X and S column halves ---
    dequant_kernel<<<dim3(12, 4, 32), 256, 0, stream>>>(gW, E, Wt, 128);
    gemm_graph_kernel<<<dim3(16, 64), 256, 0, stream>>>(
        Ah, S2h, TX0T, TS0T, TX1, TS1, TX2, TS2, 32);
    pernode_gate_kernel<<<N_NODES, 256, 0, stream>>>(
        TX0, TS0, TX1, TS1, TX2, TS2, Wt, E, gb, state, rbuf, TS0, TS0T);

    // --- avwgcn #2 (update): x-half of T1/T2 unchanged — S columns only ---
    dequant_kernel<<<dim3(12, 2, 32), 256, 0, stream>>>(uW, E, Wt, 64);
    gemm_graph_kernel<<<dim3(16, 32), 256, 0, stream>>>(
        Ah, S2h, TX0T, TS0T, TX1, TS1, TX2, TS2, 0);
    pernode_upd_kernel<<<N_NODES, 256, 0, stream>>>(
        TX0, TS0, TX1, TS1, TX2, TS2, Wt, E, ub, state, rbuf, out);
}